// Round 1
// baseline (93.480 us; speedup 1.0000x reference)
//
#include <hip/hip_runtime.h>
#include <math.h>

#define HH 32
#define WW 32
#define HW 1024
#define NB 16
#define TMAXS 1024

#pragma clang fp contract(off)

__device__ __forceinline__ float keyval(float g, float h) {
#pragma clang fp contract(off)
  const float INV = 0.17677669529663687f; // fl32(1/sqrt(32))
  float f = 0.5f * g + 0.5f * h;          // both products exact (x0.5)
  return expf(-f * INV);
}

// ---------------------------------------------------------------------------
// Kernel 1: per-batch A* search. One block (one wave, 64 lanes) per batch.
// State in LDS: key (f_exp), g, h, cm, parents (u16), flags (om|open|hist).
// Early-exits at the first goal selection: proven fixed point of the
// reference scan (subsequent steps are idempotent), so s_b = settle step and
// t = max_b s_b reproduces the reference's global `done`/`t` semantics.
// Writes: hist -> out[0..16K), parents(as float) -> out[16K..32K) (scratch,
// overwritten by kernel 2 with the path), s_b -> meta[b] in d_ws.
// ---------------------------------------------------------------------------
extern "C" __global__ void __launch_bounds__(64) astar_fwd(
    const float* __restrict__ cm_g, const float* __restrict__ sm_g,
    const float* __restrict__ gm_g, const float* __restrict__ om_g,
    float* __restrict__ out, int* __restrict__ meta) {
#pragma clang fp contract(off)
  const int b = blockIdx.x;
  const int lane = threadIdx.x;
  __shared__ __align__(16) float key[HW];
  __shared__ __align__(16) float gS[HW];
  __shared__ __align__(16) float hS[HW];
  __shared__ __align__(16) float cmS[HW];
  __shared__ unsigned short par[HW];
  __shared__ unsigned char flg[HW]; // bit0: free(om), bit1: open, bit2: hist

  const float* cm = cm_g + b * HW;
  const float* sm = sm_g + b * HW;
  const float* gm = gm_g + b * HW;
  const float* om = om_g + b * HW;

  int gi = -1, si = -1;
#pragma unroll
  for (int q = 0; q < 4; ++q) {
    const int base = q * 256 + lane * 4;
    float4 c4 = *(const float4*)(cm + base);
    float4 s4 = *(const float4*)(sm + base);
    float4 g4 = *(const float4*)(gm + base);
    float4 o4 = *(const float4*)(om + base);
    *(float4*)(cmS + base) = c4;
    float sv[4] = {s4.x, s4.y, s4.z, s4.w};
    float gv[4] = {g4.x, g4.y, g4.z, g4.w};
    float ov[4] = {o4.x, o4.y, o4.z, o4.w};
#pragma unroll
    for (int j = 0; j < 4; ++j) {
      flg[base + j] = (ov[j] > 0.5f) ? 1 : 0;
      if (gv[j] > 0.5f) gi = base + j;
      if (sv[j] > 0.5f) si = base + j;
    }
  }
#pragma unroll
  for (int m = 32; m >= 1; m >>= 1) {
    int og = __shfl_xor(gi, m, 64);
    int os = __shfl_xor(si, m, 64);
    gi = (og > gi) ? og : gi;
    si = (os > si) ? os : si;
  }
  const int goal = gi;
  const int start = si;

  // Heuristic h = Chebyshev + 0.001*euclid (+ cm), exact fp32 op order as ref.
  const float gr = (float)(goal >> 5), gc = (float)(goal & 31);
#pragma unroll
  for (int q = 0; q < 4; ++q) {
    const int base = q * 256 + lane * 4;
#pragma unroll
    for (int j = 0; j < 4; ++j) {
      const int cell = base + j;
      const float rr = (float)(cell >> 5), cc = (float)(cell & 31);
      const float dr = fabsf(rr - gr), dc = fabsf(cc - gc);
      const float h0 = (dr + dc) - fminf(dr, dc); // == max(dr,dc), exact ints
      const float euc = sqrtf(dr * dr + dc * dc); // exact int radicand
      const float t1 = 0.001f * euc;              // contract(off): no fma here
      const float hh = h0 + t1;
      hS[cell] = hh + cmS[cell];
      gS[cell] = 0.0f;
      key[cell] = 0.0f;
      par[cell] = (unsigned short)goal; // parents0 = goal broadcast
    }
  }
  __syncthreads();
  if (lane == 0) {
    flg[start] = (unsigned char)(flg[start] | 2); // open = start map
    key[start] = keyval(0.0f, hS[start]);
  }
  __syncthreads();

  int s_b = TMAXS - 1; // if never settled: contributes 1023 to t (done never)
  for (int step = 0; step < TMAXS; ++step) {
    // argmax over all 1024 keys, tie-break lowest flat index (= jnp.argmax
    // incl. the degenerate all-zero-open case -> index 0)
    float best = -1.0f;
    int bi = 0;
#pragma unroll
    for (int q = 0; q < 4; ++q) {
      const int base = q * 256 + lane * 4;
      float4 k4 = *(const float4*)(key + base);
      if (k4.x > best) { best = k4.x; bi = base; }
      if (k4.y > best) { best = k4.y; bi = base + 1; }
      if (k4.z > best) { best = k4.z; bi = base + 2; }
      if (k4.w > best) { best = k4.w; bi = base + 3; }
    }
#pragma unroll
    for (int m = 32; m >= 1; m >>= 1) {
      float ov = __shfl_xor(best, m, 64);
      int oi = __shfl_xor(bi, m, 64);
      if (ov > best || (ov == best && oi < bi)) { best = ov; bi = oi; }
    }
    const int sel = bi;
    const bool isg = (sel == goal);
    const float g2 = gS[sel] + cmS[sel]; // single fp32 add, as in ref expand
    const int r = sel >> 5, c = sel & 31;

    // relax the 8-ring (lanes 0..7). idx = ((!open&&!hist) || (open&&g>g2))*om
    if (lane < 8) {
      const int k = (lane < 4) ? lane : lane + 1; // skip center
      const int nr = r + k / 3 - 1, nc = c + k % 3 - 1;
      if (nr >= 0 && nr < HH && nc >= 0 && nc < WW) {
        const int n = (nr << 5) | nc;
        const unsigned char f = flg[n];
        if (f & 1) {
          const bool open = (f & 2) != 0, hb = (f & 4) != 0;
          if ((!open && !hb) || (open && gS[n] > g2)) {
            gS[n] = g2;
            flg[n] = (unsigned char)(f | 2);
            par[n] = (unsigned short)sel;
            key[n] = keyval(g2, hS[n]);
          }
        }
      }
    }
    if (lane == 0) {
      if (isg) {
        flg[sel] = (unsigned char)(flg[sel] | 4); // goal stays open
      } else {
        flg[sel] = (unsigned char)((flg[sel] | 4) & ~2); // close, pop
        key[sel] = 0.0f;
      }
    }
    __syncthreads();
    if (isg) { s_b = step; break; } // fixed point: all later steps idempotent
  }

  // epilogue: hist floats + parents (as floats, scratch in path region)
#pragma unroll
  for (int q = 0; q < 4; ++q) {
    const int base = q * 256 + lane * 4;
    float4 h4, p4;
    h4.x = (flg[base + 0] & 4) ? 1.0f : 0.0f;
    h4.y = (flg[base + 1] & 4) ? 1.0f : 0.0f;
    h4.z = (flg[base + 2] & 4) ? 1.0f : 0.0f;
    h4.w = (flg[base + 3] & 4) ? 1.0f : 0.0f;
    p4.x = (float)par[base + 0];
    p4.y = (float)par[base + 1];
    p4.z = (float)par[base + 2];
    p4.w = (float)par[base + 3];
    *(float4*)(out + b * HW + base) = h4;
    *(float4*)(out + NB * HW + b * HW + base) = p4;
  }
  if (lane == 0) meta[b] = s_b;
}

// ---------------------------------------------------------------------------
// Kernel 2: t = max_b s_b; backtrack parents from goal, marking path cells.
// The walk is cut when it re-enters an already-marked cell: the parent map is
// a deterministic function, so the remaining (t - i) hops replay only marked
// cells — identical marked set as the reference's full t-iteration fori_loop.
// ---------------------------------------------------------------------------
extern "C" __global__ void __launch_bounds__(64) astar_bt(
    const float* __restrict__ gm_g, float* __restrict__ out,
    const int* __restrict__ meta) {
  const int b = blockIdx.x;
  const int lane = threadIdx.x;
  __shared__ unsigned short par[HW];
  __shared__ float path[HW];

  float* pout = out + NB * HW + b * HW; // parents stored here by kernel 1
  const float* gm = gm_g + b * HW;

  int gi = -1;
#pragma unroll
  for (int q = 0; q < 4; ++q) {
    const int base = q * 256 + lane * 4;
    float4 g4 = *(const float4*)(gm + base);
    float4 p4 = *(const float4*)(pout + base);
    par[base + 0] = (unsigned short)p4.x;
    par[base + 1] = (unsigned short)p4.y;
    par[base + 2] = (unsigned short)p4.z;
    par[base + 3] = (unsigned short)p4.w;
    path[base + 0] = 0.0f;
    path[base + 1] = 0.0f;
    path[base + 2] = 0.0f;
    path[base + 3] = 0.0f;
    if (g4.x > 0.5f) gi = base;
    if (g4.y > 0.5f) gi = base + 1;
    if (g4.z > 0.5f) gi = base + 2;
    if (g4.w > 0.5f) gi = base + 3;
  }
#pragma unroll
  for (int m = 32; m >= 1; m >>= 1) {
    int og = __shfl_xor(gi, m, 64);
    gi = (og > gi) ? og : gi;
  }
  const int goal = gi;

  int t = 0;
  for (int i = 0; i < NB; ++i) {
    int s = meta[i];
    t = (s > t) ? s : t;
  }
  __syncthreads();
  if (lane == 0) {
    path[goal] = 1.0f;
    int loc = par[goal];
    for (int i = 0; i < t; ++i) {
      if (path[loc] == 1.0f) break; // deterministic replay of marked cells
      path[loc] = 1.0f;
      loc = par[loc];
    }
  }
  __syncthreads();
#pragma unroll
  for (int q = 0; q < 4; ++q) {
    const int base = q * 256 + lane * 4;
    float4 o4;
    o4.x = path[base + 0];
    o4.y = path[base + 1];
    o4.z = path[base + 2];
    o4.w = path[base + 3];
    *(float4*)(pout + base) = o4;
  }
}

extern "C" void kernel_launch(void* const* d_in, const int* in_sizes, int n_in,
                              void* d_out, int out_size, void* d_ws,
                              size_t ws_size, hipStream_t stream) {
  const float* cm = (const float*)d_in[0];
  const float* sm = (const float*)d_in[1];
  const float* gm = (const float*)d_in[2];
  const float* om = (const float*)d_in[3];
  float* out = (float*)d_out;
  int* meta = (int*)d_ws;
  hipLaunchKernelGGL(astar_fwd, dim3(NB), dim3(64), 0, stream, cm, sm, gm, om,
                     out, meta);
  hipLaunchKernelGGL(astar_bt, dim3(NB), dim3(64), 0, stream, gm, out, meta);
}

// Round 2
// 79.874 us; speedup vs baseline: 1.1703x; 1.1703x over previous
//
#include <hip/hip_runtime.h>
#include <math.h>

#define HH 32
#define WW 32
#define HW 1024
#define NB 16
#define TMAXS 1024

typedef unsigned long long ull;

// f = 0.5*g + 0.5*h, key = exp(-f/sqrt(32)) — bit-identical op order to the
// reference (and to the round-1 kernel that validated absmax==0).
__device__ __forceinline__ float keyval(float g, float h) {
#pragma clang fp contract(off)
  const float INV = 0.17677669529663687f; // fl32(1/sqrt(32))
  float f = 0.5f * g + 0.5f * h;
  return expf(-f * INV);
}

// One DPP reduction stage on a packed-f64 value: shift both 32-bit halves
// from the same source lane (invalid lanes -> 0.0 = identity for max of
// nonnegative packed values), then v_max_f64.
template <int CTRL>
__device__ __forceinline__ double dpp_fmax64(double x) {
  ull u = (ull)__double_as_longlong(x);
  int lo = (int)(unsigned)u;
  int hi = (int)(unsigned)(u >> 32);
  int lo2 = __builtin_amdgcn_update_dpp(0, lo, CTRL, 0xF, 0xF, false);
  int hi2 = __builtin_amdgcn_update_dpp(0, hi, CTRL, 0xF, 0xF, false);
  double y = __longlong_as_double(
      (long long)(((ull)(unsigned)hi2 << 32) | (unsigned)lo2));
  return fmax(x, y);
}

// ---------------------------------------------------------------------------
// Fused per-batch A* search + backtrack. One block = one wave = one batch.
//
// key2[n] packs (f64(exp-key) | (1023-n)): unique values, so v_max_f64 is an
// exact argmax with jnp's lowest-index tie-break (any open cell's packed
// value >= ~2^-1022 beats any closed cell's denormal 0..1023; among closed
// cells, lowest index wins — matching argmax over an all-zero f_exp row).
//
// No __syncthreads: single wave, DS pipe processes this wave's LDS ops in
// order; wave_barrier() pins compiler ordering at the communication points.
//
// Early-exit at first goal selection: the post-selection state is a fixed
// point of the reference scan (goal stays strict argmax: any neighbor's f
// exceeds f_goal by >= 0.5*h_nbr >= 0.5, i.e. key ratio <= e^-0.088), and
// the goal-step ring relax is output-invariant (touches only g/open/parents
// of non-hist cells, never hist; all backtrack-chain cells are hist).
//
// Backtrack fused per-batch: the walk self-terminates at the first already-
// marked cell after L_b <= s_b hops; the reference's global t = max_b s_b
// >= L_b only adds no-op re-marks, so the marked set is identical.
// ---------------------------------------------------------------------------
extern "C" __global__ void __launch_bounds__(64) astar_fused(
    const float* __restrict__ cm_g, const float* __restrict__ sm_g,
    const float* __restrict__ gm_g, const float* __restrict__ om_g,
    float* __restrict__ out) {
#pragma clang fp contract(off)
  const int b = blockIdx.x;
  const int lane = threadIdx.x;

  __shared__ __align__(16) ull key2[HW];     // packed argmax keys
  __shared__ __align__(16) float4 gch[HW];   // {g, cm, g+cm, h_full}
  __shared__ unsigned int flg[HW];           // bit0 free, bit1 open, bit2 hist
  __shared__ unsigned int par[HW];           // parent idx | mark bit31

  const float* cm = cm_g + b * HW;
  const float* sm = sm_g + b * HW;
  const float* gm = gm_g + b * HW;
  const float* om = om_g + b * HW;

  // ---- init pass 1: load inputs, find goal/start ----
  float cml[16], oml[16];
  int gi = -1, si = -1;
#pragma unroll
  for (int q = 0; q < 16; ++q) {
    const int cell = q * 64 + lane;
    const float c = cm[cell], s = sm[cell], g = gm[cell], o = om[cell];
    cml[q] = c;
    oml[q] = o;
    if (g > 0.5f) gi = cell;
    if (s > 0.5f) si = cell;
  }
#pragma unroll
  for (int m = 32; m >= 1; m >>= 1) {
    const int og = __shfl_xor(gi, m, 64);
    const int os = __shfl_xor(si, m, 64);
    gi = (og > gi) ? og : gi;
    si = (os > si) ? os : si;
  }
  const int goal = gi, start = si;

  // ---- init pass 2: h (exact ref op order), state arrays ----
  const float grf = (float)(goal >> 5), gcf = (float)(goal & 31);
#pragma unroll
  for (int q = 0; q < 16; ++q) {
    const int cell = q * 64 + lane;
    const float rr = (float)(cell >> 5), cc = (float)(cell & 31);
    const float dr = fabsf(rr - grf), dc = fabsf(cc - gcf);
    const float h0 = (dr + dc) - fminf(dr, dc); // exact (small ints)
    const float euc = sqrtf(dr * dr + dc * dc); // exact radicand
    const float t1 = 0.001f * euc;              // contract off: no fma
    const float hh = h0 + t1;
    const float hf = hh + cml[q];
    gch[cell] = make_float4(0.0f, cml[q], cml[q], hf);
    unsigned f = (oml[q] > 0.5f) ? 1u : 0u;
    ull pk = (ull)(1023 - cell);
    if (cell == start) {
      f |= 2u; // open = start map
      pk |= (ull)__double_as_longlong((double)keyval(0.0f, hf));
    }
    flg[cell] = f;
    par[cell] = (unsigned)goal; // parents0 = goal broadcast
    key2[cell] = pk;
  }

  // per-lane ring offset (lanes 0..7), constant across steps
  int dro = 0, dco = 0;
  if (lane < 8) {
    const int k = (lane < 4) ? lane : lane + 1; // skip center
    dro = k / 3 - 1;
    dco = k % 3 - 1;
  }
  const float* gchf = (const float*)gch;
  __builtin_amdgcn_wave_barrier();

  // ---- main A* loop ----
#pragma unroll 1
  for (int step = 0; step < TMAXS; ++step) {
    // stripe scan: 8 x ds_read_b128, depth-3 v_max_f64 tree
    double s[8];
#pragma unroll
    for (int q = 0; q < 8; ++q) {
      const ulonglong2 v = *(const ulonglong2*)&key2[q * 128 + lane * 2];
      s[q] = fmax(__longlong_as_double((long long)v.x),
                  __longlong_as_double((long long)v.y));
    }
    const double t0 = fmax(s[0], s[1]), t1 = fmax(s[2], s[3]);
    const double t2 = fmax(s[4], s[5]), t3 = fmax(s[6], s[7]);
    double mm = fmax(fmax(t0, t1), fmax(t2, t3));

    // wave argmax to lane 63 via DPP, then scalar broadcast
    mm = dpp_fmax64<0x111>(mm); // row_shr:1
    mm = dpp_fmax64<0x112>(mm); // row_shr:2
    mm = dpp_fmax64<0x114>(mm); // row_shr:4
    mm = dpp_fmax64<0x118>(mm); // row_shr:8
    mm = dpp_fmax64<0x142>(mm); // row_bcast:15
    mm = dpp_fmax64<0x143>(mm); // row_bcast:31
    const int lo63 =
        __builtin_amdgcn_readlane((int)(unsigned)(ull)__double_as_longlong(mm), 63);
    const int sel = 1023 - (lo63 & 1023);

    if (sel == goal) {
      if (lane == 0) flg[goal] |= 4u; // hist includes goal; stays open
      break;                          // fixed point; relax is output-invariant
    }

    if (lane < 9) {
      if (lane < 8) {
        const int nr = (sel >> 5) + dro, nc = (sel & 31) + dco;
        if ((unsigned)nr < 32u && (unsigned)nc < 32u) {
          const int n = (nr << 5) | nc;
          const unsigned f = flg[n];
          const float4 v = gch[n];               // {g, cm, g+cm, h}
          const float g2 = gchf[4 * sel + 2];    // broadcast read g[sel]+cm[sel]
          const bool upd =
              (f & 1u) && (((f & 6u) == 0u) || (((f & 2u) != 0u) && (v.x > g2)));
          if (upd) {
            gch[n] = make_float4(g2, v.y, g2 + v.y, v.w);
            flg[n] = f | 2u;
            par[n] = (unsigned)sel;
            const float kk = keyval(g2, v.w);
            key2[n] = ((ull)__double_as_longlong((double)kk)) | (ull)(1023 - n);
          }
        }
      } else { // lane 8: pop selected cell
        const unsigned fs = flg[sel];
        flg[sel] = (fs | 4u) & ~2u;
        key2[sel] = (ull)(1023 - sel);
      }
    }
    __builtin_amdgcn_wave_barrier();
  }

  // ---- fused backtrack (lane 0): mark path via par bit31 ----
  __builtin_amdgcn_wave_barrier();
  if (lane == 0) {
    const unsigned pv = par[goal];
    par[goal] = pv | 0x80000000u; // path starts as goal one-hot
    unsigned loc = pv & 1023u;
#pragma unroll 1
    for (int i = 0; i < HW; ++i) {
      const unsigned v = par[loc];
      if (v & 0x80000000u) break; // deterministic replay of marked cells
      par[loc] = v | 0x80000000u;
      loc = v & 1023u;
    }
  }
  __builtin_amdgcn_wave_barrier();

  // ---- epilogue: hist + path ----
#pragma unroll
  for (int q = 0; q < 4; ++q) {
    const int base = q * 256 + lane * 4;
    float4 hv, pv;
    hv.x = (flg[base + 0] & 4u) ? 1.0f : 0.0f;
    hv.y = (flg[base + 1] & 4u) ? 1.0f : 0.0f;
    hv.z = (flg[base + 2] & 4u) ? 1.0f : 0.0f;
    hv.w = (flg[base + 3] & 4u) ? 1.0f : 0.0f;
    pv.x = (par[base + 0] >> 31) ? 1.0f : 0.0f;
    pv.y = (par[base + 1] >> 31) ? 1.0f : 0.0f;
    pv.z = (par[base + 2] >> 31) ? 1.0f : 0.0f;
    pv.w = (par[base + 3] >> 31) ? 1.0f : 0.0f;
    *(float4*)(out + b * HW + base) = hv;
    *(float4*)(out + NB * HW + b * HW + base) = pv;
  }
}

extern "C" void kernel_launch(void* const* d_in, const int* in_sizes, int n_in,
                              void* d_out, int out_size, void* d_ws,
                              size_t ws_size, hipStream_t stream) {
  const float* cm = (const float*)d_in[0];
  const float* sm = (const float*)d_in[1];
  const float* gm = (const float*)d_in[2];
  const float* om = (const float*)d_in[3];
  float* out = (float*)d_out;
  hipLaunchKernelGGL(astar_fused, dim3(NB), dim3(64), 0, stream, cm, sm, gm,
                     om, out);
}

// Round 3
// 78.397 us; speedup vs baseline: 1.1924x; 1.0188x over previous
//
#include <hip/hip_runtime.h>
#include <math.h>

#define HW 1024
#define NB 16
#define TMAXS 1024

typedef unsigned long long ull;

__device__ __forceinline__ double u2d(ull u) {
  return __longlong_as_double((long long)u);
}
__device__ __forceinline__ ull d2u(double d) {
  return (ull)__double_as_longlong(d);
}

// f = 0.5*g + 0.5*h, key = exp(-f/sqrt(32)) — bit-identical op order to the
// reference (validated absmax==0 in rounds 1-2).
__device__ __forceinline__ float keyval(float g, float h) {
#pragma clang fp contract(off)
  const float INV = 0.17677669529663687f; // fl32(1/sqrt(32))
  float f = 0.5f * g + 0.5f * h;
  return expf(-f * INV);
}

// One DPP reduction stage on a packed-f64 value (positive; invalid source
// lanes contribute 0.0 = identity). Chain validated in round 2.
template <int CTRL>
__device__ __forceinline__ double dpp_fmax64(double x) {
  ull u = d2u(x);
  int lo = (int)(unsigned)u;
  int hi = (int)(unsigned)(u >> 32);
  int lo2 = __builtin_amdgcn_update_dpp(0, lo, CTRL, 0xF, 0xF, false);
  int hi2 = __builtin_amdgcn_update_dpp(0, hi, CTRL, 0xF, 0xF, false);
  double y = u2d(((ull)(unsigned)hi2 << 32) | (unsigned)lo2);
  return fmax(x, y);
}

// ---------------------------------------------------------------------------
// Fused per-batch A* + backtrack, one wave per batch, with the 1024-key scan
// software-pipelined across iterations:
//   iter i entry: sel_i known; scan regs r[] hold S_{i-1} (reads issued in
//   iter i-1 AFTER its relax writes — DS pipe is in-order per wave).
//   argmax(S_i) = max( tree(r with cell==sel_i -> denorm)   [pop_i patch]
//                    , ring_i new keys folded from registers [increase-only] )
//   Exactness: relaxation only increases keys (g strictly decreases -> f
//   decreases -> expf monotone); the pop is the only decrease and is patched
//   by index; ring excludes the center so the patches never collide.
//   sel_0 = start (the only open cell at step 0).
// Early-exit at first goal selection + fused per-batch backtrack: same
// fixed-point / invariance proofs as rounds 1-2 (validated absmax 0).
// ---------------------------------------------------------------------------
extern "C" __global__ void __launch_bounds__(64) astar_fused(
    const float* __restrict__ cm_g, const float* __restrict__ sm_g,
    const float* __restrict__ gm_g, const float* __restrict__ om_g,
    float* __restrict__ out) {
#pragma clang fp contract(off)
  const int b = blockIdx.x;
  const int lane = threadIdx.x;

  __shared__ __align__(16) ull key2[HW];   // packed (f64(key) | 1023-idx)
  __shared__ __align__(16) float4 gch[HW]; // {g, cm, g+cm, h_full}
  __shared__ __align__(16) unsigned flg[HW]; // bit0 free, bit1 open, bit2 hist
  __shared__ __align__(16) unsigned par[HW]; // parent | mark bit31
  const float* gchf = (const float*)gch;

  const float* cm = cm_g + b * HW;
  const float* sm = sm_g + b * HW;
  const float* gm = gm_g + b * HW;
  const float* om = om_g + b * HW;

  // ---- init pass 1: vectorized loads, locate goal/start ----
  float4 c4[4], o4[4];
  int gi = -1, si = -1;
#pragma unroll
  for (int q = 0; q < 4; ++q) {
    const int base = q * 256 + lane * 4;
    c4[q] = *(const float4*)(cm + base);
    o4[q] = *(const float4*)(om + base);
    const float4 s4 = *(const float4*)(sm + base);
    const float4 g4 = *(const float4*)(gm + base);
    const float sv[4] = {s4.x, s4.y, s4.z, s4.w};
    const float gv[4] = {g4.x, g4.y, g4.z, g4.w};
#pragma unroll
    for (int j = 0; j < 4; ++j) {
      if (gv[j] > 0.5f) gi = base + j;
      if (sv[j] > 0.5f) si = base + j;
    }
  }
#pragma unroll
  for (int m = 32; m >= 1; m >>= 1) {
    const int og = __shfl_xor(gi, m, 64);
    const int os = __shfl_xor(si, m, 64);
    gi = (og > gi) ? og : gi;
    si = (os > si) ? os : si;
  }
  const int goal = gi, start = si;

  // ---- init pass 2: h (exact ref op order), state arrays, vector writes ----
  const float grf = (float)(goal >> 5), gcf = (float)(goal & 31);
#pragma unroll
  for (int q = 0; q < 4; ++q) {
    const int base = q * 256 + lane * 4;
    const float cv[4] = {c4[q].x, c4[q].y, c4[q].z, c4[q].w};
    const float ov[4] = {o4[q].x, o4[q].y, o4[q].z, o4[q].w};
    ull pk[4];
    unsigned fv[4];
#pragma unroll
    for (int j = 0; j < 4; ++j) {
      const int cell = base + j;
      const float rr = (float)(cell >> 5), cc = (float)(cell & 31);
      const float dr = fabsf(rr - grf), dc = fabsf(cc - gcf);
      const float h0 = (dr + dc) - fminf(dr, dc); // exact (small ints)
      const float euc = sqrtf(dr * dr + dc * dc); // exact radicand
      const float t1 = 0.001f * euc;              // contract off: no fma
      const float hh = h0 + t1;
      const float hf = hh + cv[j];
      gch[cell] = make_float4(0.0f, cv[j], cv[j], hf);
      fv[j] = (ov[j] > 0.5f) ? 1u : 0u;
      pk[j] = (ull)(1023 - cell);
      if (cell == start) {
        fv[j] |= 2u; // open = start map
        pk[j] |= d2u((double)keyval(0.0f, hf));
      }
    }
    *(uint4*)&flg[base] = make_uint4(fv[0], fv[1], fv[2], fv[3]);
    *(uint4*)&par[base] =
        make_uint4((unsigned)goal, (unsigned)goal, (unsigned)goal, (unsigned)goal);
    ulonglong2 k01, k23;
    k01.x = pk[0]; k01.y = pk[1];
    k23.x = pk[2]; k23.y = pk[3];
    *(ulonglong2*)&key2[base] = k01;
    *(ulonglong2*)&key2[base + 2] = k23;
  }
  __builtin_amdgcn_wave_barrier();

  // prefetched scan of the initial state S_{-1}
  ulonglong2 r[8];
#pragma unroll
  for (int q = 0; q < 8; ++q)
    r[q] = *(const ulonglong2*)&key2[q * 128 + lane * 2];

  int dro = 0, dco = 0;
  if (lane < 8) {
    const int k = (lane < 4) ? lane : lane + 1; // skip center
    dro = k / 3 - 1;
    dco = k % 3 - 1;
  }

  int sel = start; // step-0 argmax: start is the only open cell
  bool reached = false;

#pragma unroll 1
  for (int step = 0; step < TMAXS; ++step) {
    if (sel == goal) { reached = true; break; }

    // -- relax reads (issue early; single DS latency window) --
    const float g2 = gchf[4 * sel + 2]; // broadcast: g[sel]+cm[sel]
    int n = -1;
    unsigned f = 0;
    float4 v = make_float4(0.f, 0.f, 0.f, 0.f);
    if (lane < 8) {
      const int nr = (sel >> 5) + dro, nc = (sel & 31) + dco;
      if ((unsigned)nr < 32u && (unsigned)nc < 32u) {
        n = (nr << 5) | nc;
        f = flg[n];
        v = gch[n];
      }
    }
    unsigned fs = 0;
    if (lane == 8) fs = flg[sel];

    // -- local tree over prefetched S_{i-1}, patching pop(sel) --
    double m = 0.0;
#pragma unroll
    for (int q = 0; q < 8; ++q) {
      const int base = q * 128 + lane * 2;
      const ull a = (base == sel) ? (ull)(1023 - base) : r[q].x;
      const ull c = (base + 1 == sel) ? (ull)(1022 - base) : r[q].y;
      m = fmax(m, fmax(u2d(a), u2d(c)));
    }

    // -- relax compute + writes + fold of increases --
    if (lane < 8 && n >= 0) {
      const bool upd =
          (f & 1u) && (((f & 6u) == 0u) || (((f & 2u) != 0u) && (v.x > g2)));
      if (upd) {
        gch[n] = make_float4(g2, v.y, g2 + v.y, v.w);
        flg[n] = f | 2u;
        par[n] = (unsigned)sel;
        const ull pk = d2u((double)keyval(g2, v.w)) | (ull)(1023 - n);
        key2[n] = pk;
        m = fmax(m, u2d(pk)); // ring increase folded in registers
      }
    }
    if (lane == 8) { // pop
      flg[sel] = (fs | 4u) & ~2u;
      key2[sel] = (ull)(1023 - sel);
    }
    __builtin_amdgcn_wave_barrier();

    // -- prefetch scan of S_i for the next iteration (after the writes) --
#pragma unroll
    for (int q = 0; q < 8; ++q)
      r[q] = *(const ulonglong2*)&key2[q * 128 + lane * 2];

    // -- wave argmax reduce --
    m = dpp_fmax64<0x111>(m); // row_shr:1
    m = dpp_fmax64<0x112>(m); // row_shr:2
    m = dpp_fmax64<0x114>(m); // row_shr:4
    m = dpp_fmax64<0x118>(m); // row_shr:8
    m = dpp_fmax64<0x142>(m); // row_bcast:15
    m = dpp_fmax64<0x143>(m); // row_bcast:31
    const int lo63 = __builtin_amdgcn_readlane((int)(unsigned)d2u(m), 63);
    sel = 1023 - (lo63 & 1023);
  }
  if (reached && lane == 0) flg[goal] |= 4u; // hist includes goal
  __builtin_amdgcn_wave_barrier();

  // ---- fused backtrack (lane 0): mark path via par bit31 ----
  if (lane == 0) {
    const unsigned pv = par[goal];
    par[goal] = pv | 0x80000000u; // path starts as goal one-hot
    unsigned loc = pv & 1023u;
#pragma unroll 1
    for (int i = 0; i < HW; ++i) {
      const unsigned w = par[loc];
      if (w & 0x80000000u) break; // deterministic replay of marked cells
      par[loc] = w | 0x80000000u;
      loc = w & 1023u;
    }
  }
  __builtin_amdgcn_wave_barrier();

  // ---- epilogue: hist + path ----
#pragma unroll
  for (int q = 0; q < 4; ++q) {
    const int base = q * 256 + lane * 4;
    float4 hv, pv;
    hv.x = (flg[base + 0] & 4u) ? 1.0f : 0.0f;
    hv.y = (flg[base + 1] & 4u) ? 1.0f : 0.0f;
    hv.z = (flg[base + 2] & 4u) ? 1.0f : 0.0f;
    hv.w = (flg[base + 3] & 4u) ? 1.0f : 0.0f;
    pv.x = (par[base + 0] >> 31) ? 1.0f : 0.0f;
    pv.y = (par[base + 1] >> 31) ? 1.0f : 0.0f;
    pv.z = (par[base + 2] >> 31) ? 1.0f : 0.0f;
    pv.w = (par[base + 3] >> 31) ? 1.0f : 0.0f;
    *(float4*)(out + b * HW + base) = hv;
    *(float4*)(out + NB * HW + b * HW + base) = pv;
  }
}

extern "C" void kernel_launch(void* const* d_in, const int* in_sizes, int n_in,
                              void* d_out, int out_size, void* d_ws,
                              size_t ws_size, hipStream_t stream) {
  const float* cm = (const float*)d_in[0];
  const float* sm = (const float*)d_in[1];
  const float* gm = (const float*)d_in[2];
  const float* om = (const float*)d_in[3];
  float* out = (float*)d_out;
  hipLaunchKernelGGL(astar_fused, dim3(NB), dim3(64), 0, stream, cm, sm, gm,
                     om, out);
}

// Round 4
// 77.626 us; speedup vs baseline: 1.2042x; 1.0099x over previous
//
#include <hip/hip_runtime.h>
#include <math.h>

#define HW 1024
#define NB 16
#define TMAXS 1024

typedef unsigned long long ull;

__device__ __forceinline__ double u2d(ull u) {
  return __longlong_as_double((long long)u);
}
__device__ __forceinline__ ull d2u(double d) {
  return (ull)__double_as_longlong(d);
}

// f = 0.5*g + 0.5*h, key = exp(-f/sqrt(32)) — bit-identical op order to the
// reference (validated absmax==0 in rounds 1-3).
__device__ __forceinline__ float keyval(float g, float h) {
#pragma clang fp contract(off)
  const float INV = 0.17677669529663687f; // fl32(1/sqrt(32))
  float f = 0.5f * g + 0.5f * h;
  return expf(-f * INV);
}

// One DPP reduction stage on a packed-f64 value (nonnegative; disabled
// source lanes contribute 0.0 = identity). Chain validated rounds 2-3.
template <int CTRL>
__device__ __forceinline__ double dpp_fmax64(double x) {
  ull u = d2u(x);
  int lo = (int)(unsigned)u;
  int hi = (int)(unsigned)(u >> 32);
  int lo2 = __builtin_amdgcn_update_dpp(0, lo, CTRL, 0xF, 0xF, false);
  int hi2 = __builtin_amdgcn_update_dpp(0, hi, CTRL, 0xF, 0xF, false);
  double y = u2d(((ull)(unsigned)hi2 << 32) | (unsigned)lo2);
  return fmax(x, y);
}

// ---------------------------------------------------------------------------
// Fused per-batch A* + backtrack, one wave per batch, with an INCREMENTAL
// hierarchical argmax replacing the full 1024-key scan:
//   level1[g] = max over cells [16g,16g+16) of packed (f64(key)|1023-idx).
//   Maintained exactly:
//     - relax increases -> atomicMax (ds_max_u64; nonneg doubles compare
//       correctly as u64; relaxation strictly increases a cell's key)
//     - pop (the only decrease) -> level1[gp]=0 at iter start, then lanes
//       32..47 re-atomicMax the group's 16 keys (read from S_{i-1}, sel
//       patched to its denormal) — order-hazard-free since everything after
//       the zero store is an increase, and the wave's DS ops are in-order.
//   Per-iter reduce input (covers exactly S_i):
//     lane g: stale level1[g] (read issued at END of prev iter, after all
//             its writes -> exact for S_{i-1}), zeroed for g==gp;
//     lanes 32..47 fold the patched group-gp cells;
//     relax lanes fold their fresh pk (ring increases).
//   Then the validated 6-stage DPP-f64 max -> readlane -> sel.
// Early-exit at first goal selection + fused per-batch backtrack: same
// fixed-point / invariance proofs as rounds 1-3 (validated absmax 0).
// ---------------------------------------------------------------------------
extern "C" __global__ void __launch_bounds__(64) astar_fused(
    const float* __restrict__ cm_g, const float* __restrict__ sm_g,
    const float* __restrict__ gm_g, const float* __restrict__ om_g,
    float* __restrict__ out) {
#pragma clang fp contract(off)
  const int b = blockIdx.x;
  const int lane = threadIdx.x;

  __shared__ __align__(16) ull key2[HW];     // packed (f64(key) | 1023-idx)
  __shared__ __align__(16) float4 gch[HW];   // {g, cm, g+cm, h_full}
  __shared__ __align__(16) unsigned flg[HW]; // bit0 free, bit1 open, bit2 hist
  __shared__ __align__(16) unsigned par[HW]; // parent | mark bit31
  __shared__ __align__(16) ull level1[64];   // per-16-cell-group max
  const float* gchf = (const float*)gch;

  const float* cm = cm_g + b * HW;
  const float* sm = sm_g + b * HW;
  const float* gm = gm_g + b * HW;
  const float* om = om_g + b * HW;

  // ---- init pass 1: vectorized loads, locate goal/start ----
  float4 c4[4], o4[4];
  int gi = -1, si = -1;
#pragma unroll
  for (int q = 0; q < 4; ++q) {
    const int base = q * 256 + lane * 4;
    c4[q] = *(const float4*)(cm + base);
    o4[q] = *(const float4*)(om + base);
    const float4 s4 = *(const float4*)(sm + base);
    const float4 g4 = *(const float4*)(gm + base);
    const float sv[4] = {s4.x, s4.y, s4.z, s4.w};
    const float gv[4] = {g4.x, g4.y, g4.z, g4.w};
#pragma unroll
    for (int j = 0; j < 4; ++j) {
      if (gv[j] > 0.5f) gi = base + j;
      if (sv[j] > 0.5f) si = base + j;
    }
  }
#pragma unroll
  for (int m = 32; m >= 1; m >>= 1) {
    const int og = __shfl_xor(gi, m, 64);
    const int os = __shfl_xor(si, m, 64);
    gi = (og > gi) ? og : gi;
    si = (os > si) ? os : si;
  }
  const int goal = gi, start = si;

  // ---- init pass 2: h (exact ref op order), state arrays, level1 ----
  level1[lane] = 0ull; // before the atomics below (same array: order kept)
  const float grf = (float)(goal >> 5), gcf = (float)(goal & 31);
#pragma unroll
  for (int q = 0; q < 4; ++q) {
    const int base = q * 256 + lane * 4;
    const float cv[4] = {c4[q].x, c4[q].y, c4[q].z, c4[q].w};
    const float ov[4] = {o4[q].x, o4[q].y, o4[q].z, o4[q].w};
    ull pk[4];
    unsigned fv[4];
#pragma unroll
    for (int j = 0; j < 4; ++j) {
      const int cell = base + j;
      const float rr = (float)(cell >> 5), cc = (float)(cell & 31);
      const float dr = fabsf(rr - grf), dc = fabsf(cc - gcf);
      const float h0 = (dr + dc) - fminf(dr, dc); // exact (small ints)
      const float euc = sqrtf(dr * dr + dc * dc); // exact radicand
      const float t1 = 0.001f * euc;              // contract off: no fma
      const float hh = h0 + t1;
      const float hf = hh + cv[j];
      gch[cell] = make_float4(0.0f, cv[j], cv[j], hf);
      fv[j] = (ov[j] > 0.5f) ? 1u : 0u;
      pk[j] = (ull)(1023 - cell);
      if (cell == start) {
        fv[j] |= 2u; // open = start map
        pk[j] |= d2u((double)keyval(0.0f, hf));
      }
      atomicMax(&level1[cell >> 4], pk[j]);
    }
    *(uint4*)&flg[base] = make_uint4(fv[0], fv[1], fv[2], fv[3]);
    *(uint4*)&par[base] =
        make_uint4((unsigned)goal, (unsigned)goal, (unsigned)goal, (unsigned)goal);
    ulonglong2 k01, k23;
    k01.x = pk[0]; k01.y = pk[1];
    k23.x = pk[2]; k23.y = pk[3];
    *(ulonglong2*)&key2[base] = k01;
    *(ulonglong2*)&key2[base + 2] = k23;
  }
  __builtin_amdgcn_wave_barrier();
  ull stale = level1[lane]; // S_{-1} group maxes

  int dro = 0, dco = 0;
  if (lane < 8) {
    const int k = (lane < 4) ? lane : lane + 1; // skip center
    dro = k / 3 - 1;
    dco = k % 3 - 1;
  }

  int sel = start; // step-0 argmax: start is the only open cell
  bool reached = false;

#pragma unroll 1
  for (int step = 0; step < TMAXS; ++step) {
    if (sel == goal) { reached = true; break; }
    const int gp = sel >> 4;

    // -- DS phase 1: zero popped group's level1; issue all reads --
    if (lane == 8) level1[gp] = 0ull;
    const float g2 = gchf[4 * sel + 2]; // broadcast: g[sel]+cm[sel]
    int n = -1;
    if (lane < 8) {
      const int nr = (sel >> 5) + dro, nc = (sel & 31) + dco;
      if ((unsigned)nr < 32u && (unsigned)nc < 32u) n = (nr << 5) | nc;
    } else if (lane == 8) {
      n = sel;
    }
    unsigned f = 0;
    if (n >= 0) f = flg[n];
    float4 v = make_float4(0.f, 0.f, 0.f, 0.f);
    if (lane < 8 && n >= 0) v = gch[n];
    ull gc = 0ull;
    const bool grpLane = (lane >= 32) && (lane < 48);
    if (grpLane) {
      const int gcell = gp * 16 + (lane - 32);
      gc = key2[gcell];
      if (gcell == sel) gc = (ull)(1023 - sel); // patch the pop
      atomicMax(&level1[gp], gc);               // rebuild group max
    }

    // -- relax compute + writes + level1 maintenance --
    bool updv = false;
    ull pk = 0ull;
    if (lane < 8 && n >= 0) {
      updv = (f & 1u) && (((f & 6u) == 0u) || (((f & 2u) != 0u) && (v.x > g2)));
      if (updv) pk = d2u((double)keyval(g2, v.w)) | (ull)(1023 - n);
    }
    if (updv) {
      gch[n] = make_float4(g2, v.y, g2 + v.y, v.w);
      par[n] = (unsigned)sel;
    }
    if (updv || lane == 8) {
      flg[n] = (lane == 8) ? ((f | 4u) & ~2u) : (f | 2u);
      key2[n] = (lane == 8) ? (ull)(1023 - sel) : pk;
    }
    if (updv) atomicMax(&level1[n >> 4], pk);

    // -- reduce over S_i: stale (gp zeroed) + group folds + ring folds --
    double m = (lane == gp) ? 0.0 : u2d(stale);
    if (grpLane) m = fmax(m, u2d(gc));
    if (updv) m = fmax(m, u2d(pk));
    m = dpp_fmax64<0x111>(m); // row_shr:1
    m = dpp_fmax64<0x112>(m); // row_shr:2
    m = dpp_fmax64<0x114>(m); // row_shr:4
    m = dpp_fmax64<0x118>(m); // row_shr:8
    m = dpp_fmax64<0x142>(m); // row_bcast:15
    m = dpp_fmax64<0x143>(m); // row_bcast:31

    // -- stale snapshot of level1(S_i) for next iter (after all writes) --
    stale = level1[lane];

    const int lo63 = __builtin_amdgcn_readlane((int)(unsigned)d2u(m), 63);
    sel = 1023 - (lo63 & 1023);
    __builtin_amdgcn_wave_barrier();
  }
  if (reached && lane == 0) flg[goal] |= 4u; // hist includes goal
  __builtin_amdgcn_wave_barrier();

  // ---- fused backtrack (lane 0): mark path via par bit31 ----
  if (lane == 0) {
    const unsigned pv = par[goal];
    par[goal] = pv | 0x80000000u; // path starts as goal one-hot
    unsigned loc = pv & 1023u;
#pragma unroll 1
    for (int i = 0; i < HW; ++i) {
      const unsigned w = par[loc];
      if (w & 0x80000000u) break; // deterministic replay of marked cells
      par[loc] = w | 0x80000000u;
      loc = w & 1023u;
    }
  }
  __builtin_amdgcn_wave_barrier();

  // ---- epilogue: hist + path ----
#pragma unroll
  for (int q = 0; q < 4; ++q) {
    const int base = q * 256 + lane * 4;
    float4 hv, pv;
    hv.x = (flg[base + 0] & 4u) ? 1.0f : 0.0f;
    hv.y = (flg[base + 1] & 4u) ? 1.0f : 0.0f;
    hv.z = (flg[base + 2] & 4u) ? 1.0f : 0.0f;
    hv.w = (flg[base + 3] & 4u) ? 1.0f : 0.0f;
    pv.x = (par[base + 0] >> 31) ? 1.0f : 0.0f;
    pv.y = (par[base + 1] >> 31) ? 1.0f : 0.0f;
    pv.z = (par[base + 2] >> 31) ? 1.0f : 0.0f;
    pv.w = (par[base + 3] >> 31) ? 1.0f : 0.0f;
    *(float4*)(out + b * HW + base) = hv;
    *(float4*)(out + NB * HW + b * HW + base) = pv;
  }
}

extern "C" void kernel_launch(void* const* d_in, const int* in_sizes, int n_in,
                              void* d_out, int out_size, void* d_ws,
                              size_t ws_size, hipStream_t stream) {
  const float* cm = (const float*)d_in[0];
  const float* sm = (const float*)d_in[1];
  const float* gm = (const float*)d_in[2];
  const float* om = (const float*)d_in[3];
  float* out = (float*)d_out;
  hipLaunchKernelGGL(astar_fused, dim3(NB), dim3(64), 0, stream, cm, sm, gm,
                     om, out);
}